// Round 3
// baseline (472.925 us; speedup 1.0000x reference)
//
#include <hip/hip_runtime.h>
#include <hip/hip_bf16.h>
#include <math.h>

#define N_NODES 50000
#define M_ITEMS 5000
#define D_FEAT 64
#define D_HID 32
#define D_EMB 64
#define N_EDGES 1200000
#define BATCH 4096
#define CAP 128   // per-node in-degree capacity; mean deg=24, P(deg>128) ~ e^-100

__device__ __forceinline__ float sigmoidf_(float z) {
    return 1.0f / (1.0f + __expf(-z));
}

// W_enc [64,5000] -> W_encT [5000,64] (coalesced writes)
__global__ void k_transpose(const float* __restrict__ W, float* __restrict__ WT) {
    int idx = blockIdx.x * blockDim.x + threadIdx.x;
    if (idx >= D_EMB * M_ITEMS) return;
    int e = idx & 63, m = idx >> 6;
    WT[idx] = W[(size_t)e * M_ITEMS + m];
}

// Bucketed reverse-CSR: cursor[dst]++ gives slot position; slot[dst][pos]=src.
__global__ void k_fill(const int* __restrict__ src, const int* __restrict__ dst,
                       int* __restrict__ cursor, int* __restrict__ slot) {
    int e = blockIdx.x * blockDim.x + threadIdx.x;
    if (e >= N_EDGES) return;
    int dn = dst[e];
    int pos = atomicAdd(&cursor[dn], 1);
    if (pos < CAP) slot[(size_t)dn * CAP + pos] = src[e];
}

// Y[r,c] = sum_k X[r,k]*W[c,k].  Weights staged TRANSPOSED in LDS.
template<int DIN, int DOUT>
__global__ void k_xw(const float* __restrict__ X, const float* __restrict__ W,
                     float* __restrict__ Y, int N) {
    __shared__ float wsT[DIN * DOUT];
    for (int j = threadIdx.x; j < DIN * DOUT; j += blockDim.x) {
        int c = j / DIN, k = j % DIN;
        wsT[k * DOUT + c] = W[j];
    }
    __syncthreads();
    int idx = blockIdx.x * blockDim.x + threadIdx.x;
    if (idx >= N * DOUT) return;
    int r = idx / DOUT, c = idx % DOUT;
    const float* xp = X + (size_t)r * DIN;
    float s = 0.f;
#pragma unroll
    for (int k = 0; k < DIN; k += 4) {
        float4 xv = *reinterpret_cast<const float4*>(xp + k);
        s = fmaf(xv.x, wsT[(k + 0) * DOUT + c], s);
        s = fmaf(xv.y, wsT[(k + 1) * DOUT + c], s);
        s = fmaf(xv.z, wsT[(k + 2) * DOUT + c], s);
        s = fmaf(xv.w, wsT[(k + 3) * DOUT + c], s);
    }
    Y[idx] = s;
}

// Broadcast slot j within a 32-lane group (slots preloaded to 4 regs/lane).
__device__ __forceinline__ int pick4_32(int s0, int s1, int s2, int s3, int j) {
    int v = (j < 32) ? s0 : (j < 64) ? s1 : (j < 96) ? s2 : s3;
    return __shfl(v, j & 31, 32);
}

// h[n,:] = relu( gather(y1)/deg + bl1 + node_x[n]@Wr1^T ); 8 nodes/block.
__global__ __launch_bounds__(256)
void k_node1(const float* __restrict__ node_x, const float* __restrict__ y1,
             const int* __restrict__ cursor, const int* __restrict__ slot,
             const float* __restrict__ Wr1, const float* __restrict__ bl1,
             float* __restrict__ h) {
    __shared__ float wt[D_FEAT * D_HID];   // Wr1 transposed: wt[k*32+c]
    for (int j = threadIdx.x; j < D_HID * D_FEAT; j += blockDim.x) {
        int c = j >> 6, k = j & 63;        // Wr1[c,k]
        wt[k * D_HID + c] = Wr1[j];
    }
    __syncthreads();
    const int lane = threadIdx.x & 31;
    const int n = blockIdx.x * 8 + (threadIdx.x >> 5);   // 50000 = 6250*8 exact
    const int dgf = cursor[n];
    const int dg = min(dgf, CAP);
    const int* sl = slot + (size_t)n * CAP;
    int s0 = (lane < dg) ? sl[lane] : 0;
    int s1 = (32 + lane < dg) ? sl[32 + lane] : 0;
    int s2 = (64 + lane < dg) ? sl[64 + lane] : 0;
    int s3 = (96 + lane < dg) ? sl[96 + lane] : 0;
    float g0 = 0.f, g1 = 0.f, g2 = 0.f, g3 = 0.f;
    int j = 0;
    for (; j + 4 <= dg; j += 4) {
        int a = pick4_32(s0, s1, s2, s3, j);
        int b = pick4_32(s0, s1, s2, s3, j + 1);
        int c = pick4_32(s0, s1, s2, s3, j + 2);
        int d = pick4_32(s0, s1, s2, s3, j + 3);
        g0 += y1[(size_t)a * D_HID + lane];
        g1 += y1[(size_t)b * D_HID + lane];
        g2 += y1[(size_t)c * D_HID + lane];
        g3 += y1[(size_t)d * D_HID + lane];
    }
    for (; j < dg; ++j)
        g0 += y1[(size_t)pick4_32(s0, s1, s2, s3, j) * D_HID + lane];
    float g = ((g0 + g1) + (g2 + g3)) / fmaxf((float)dgf, 1.f) + bl1[lane];
    const float* xp = node_x + (size_t)n * D_FEAT;
    float s = 0.f;
#pragma unroll
    for (int k = 0; k < D_FEAT; k += 4) {
        float4 xv = *reinterpret_cast<const float4*>(xp + k);
        s = fmaf(xv.x, wt[(k + 0) * D_HID + lane], s);
        s = fmaf(xv.y, wt[(k + 1) * D_HID + lane], s);
        s = fmaf(xv.z, wt[(k + 2) * D_HID + lane], s);
        s = fmaf(xv.w, wt[(k + 3) * D_HID + lane], s);
    }
    h[(size_t)n * D_HID + lane] = fmaxf(g + s, 0.f);
}

// Partial encoder: part[ky][row][e] = sum over k-chunk of rating[x[row]]@WencT.
// 32 rows/block, 8 waves split the m-chunk, LDS reduce (two 16-row passes).
__global__ __launch_bounds__(512)
void k_enc_part(const int* __restrict__ x, const float* __restrict__ rating,
                const float* __restrict__ WencT, float* __restrict__ part) {
    __shared__ float red[8][16][64];       // 32 KB
    __shared__ int ns[32];
    const int tid = threadIdx.x, lane = tid & 63, wave = tid >> 6;
    const int rb = blockIdx.x * 32;        // 128 row-blocks
    const int ky = blockIdx.y;             // 0..3 k-chunks of 320 float4-groups
    if (tid < 32) ns[tid] = x[rb + tid];
    __syncthreads();
    int nh[32];
#pragma unroll
    for (int i = 0; i < 32; ++i)
        nh[i] = __builtin_amdgcn_readfirstlane(ns[i]);   // SGPR node ids
    float acc[32];
#pragma unroll
    for (int i = 0; i < 32; ++i) acc[i] = 0.f;
    const int c0 = ky * 320, c1 = min(c0 + 320, M_ITEMS / 4);
    for (int c = c0 + wave; c < c1; c += 8) {
        int m = c * 4;
        float w0 = WencT[(size_t)(m + 0) * 64 + lane];
        float w1 = WencT[(size_t)(m + 1) * 64 + lane];
        float w2 = WencT[(size_t)(m + 2) * 64 + lane];
        float w3 = WencT[(size_t)(m + 3) * 64 + lane];
#pragma unroll
        for (int i = 0; i < 32; ++i) {
            const float4 r4 = *reinterpret_cast<const float4*>(
                &rating[(size_t)nh[i] * M_ITEMS + m]);
            acc[i] = fmaf(r4.x, w0, acc[i]);
            acc[i] = fmaf(r4.y, w1, acc[i]);
            acc[i] = fmaf(r4.z, w2, acc[i]);
            acc[i] = fmaf(r4.w, w3, acc[i]);
        }
    }
#pragma unroll
    for (int half = 0; half < 2; ++half) {
        __syncthreads();
#pragma unroll
        for (int i = 0; i < 16; ++i) red[wave][i][lane] = acc[half * 16 + i];
        __syncthreads();
#pragma unroll
        for (int i = 0; i < 2; ++i) {
            int r = wave * 2 + i;
            float s = 0.f;
#pragma unroll
            for (int w = 0; w < 8; ++w) s += red[w][r][lane];
            part[((size_t)ky * BATCH + rb + half * 16 + r) * 64 + lane] = s;
        }
    }
}

// Final combine: emb[row] = sigmoid( sum_ky part + benc
//                 + gather(h)/deg @ Wl2^T + bl2 + h[x]@Wr2^T ).  1 wave/row.
__global__ __launch_bounds__(512)
void k_comb(const int* __restrict__ x, const float* __restrict__ part,
            const float* __restrict__ benc, const int* __restrict__ cursor,
            const int* __restrict__ slot, const float* __restrict__ h,
            const float* __restrict__ Wl2, const float* __restrict__ bl2,
            const float* __restrict__ Wr2, float* __restrict__ emb) {
    __shared__ float wl2t[D_HID * D_EMB];  // Wl2 transposed: [k*64+e]
    __shared__ float wr2t[D_HID * D_EMB];
    __shared__ float aggl[8][D_HID];
    __shared__ float hl[8][D_HID];
    __shared__ int ns[8];
    const int tid = threadIdx.x, lane = tid & 63, wave = tid >> 6;
    const int rb = blockIdx.x * 8;
    if (tid < 8) ns[tid] = x[rb + tid];
    for (int j = tid; j < D_EMB * D_HID; j += 512) {
        int e = j >> 5, k = j & 31;        // W[e,k]
        wl2t[k * D_EMB + e] = Wl2[j];
        wr2t[k * D_EMB + e] = Wr2[j];
    }
    __syncthreads();
    const int row = rb + wave;
    const int node = ns[wave];
    const int dgf = cursor[node];
    const int dg = min(dgf, CAP);
    const int* sl = slot + (size_t)node * CAP;
    int s0 = (lane < dg) ? sl[lane] : 0;
    int s1 = (64 + lane < dg) ? sl[64 + lane] : 0;
    const int k32 = lane & 31, hi = lane >> 5;
    // 2 neighbors per iteration (lane halves), h is 32-wide
    float g0 = 0.f, g1 = 0.f;
    const int nt = (dg + 1) >> 1;          // neighbor pairs
    int t = 0;
    for (; t + 2 <= nt; t += 2) {
        int v0 = (2 * t < 64) ? s0 : s1;
        int v1 = (2 * t + 2 < 64) ? s0 : s1;
        int j0 = 2 * t + hi, j1 = 2 * t + 2 + hi;
        int a = __shfl(v0, j0 & 63, 64);
        int b = __shfl(v1, j1 & 63, 64);
        if (j0 < dg) g0 += h[(size_t)a * D_HID + k32];
        if (j1 < dg) g1 += h[(size_t)b * D_HID + k32];
    }
    for (; t < nt; ++t) {
        int v0 = (2 * t < 64) ? s0 : s1;
        int j0 = 2 * t + hi;
        int a = __shfl(v0, j0 & 63, 64);
        if (j0 < dg) g0 += h[(size_t)a * D_HID + k32];
    }
    float g = g0 + g1;
    g += __shfl(g, lane ^ 32, 64);         // fold halves: lanes<32 hold sum[k]
    if (lane < 32) {
        aggl[wave][k32] = g / fmaxf((float)dgf, 1.f);
        hl[wave][k32] = h[(size_t)node * D_HID + k32];
    }
    // same-wave LDS write->read; lockstep, compiler inserts waitcnt
    float ge = bl2[lane];
#pragma unroll
    for (int k = 0; k < D_HID; ++k)
        ge = fmaf(aggl[wave][k], wl2t[k * D_EMB + lane], ge);
#pragma unroll
    for (int k = 0; k < D_HID; ++k)
        ge = fmaf(hl[wave][k], wr2t[k * D_EMB + lane], ge);
    float ae = benc[lane];
#pragma unroll
    for (int ky = 0; ky < 4; ++ky)
        ae += part[((size_t)ky * BATCH + row) * 64 + lane];
    emb[(size_t)row * D_EMB + lane] = sigmoidf_(ge + ae);
}

// out[b,m] = sigmoid(dot(emb[b,:64], Wdec[m,:64]) + bdec[m]); 32 rows/block.
__global__ __launch_bounds__(256)
void k_dec(const float* __restrict__ emb, const float* __restrict__ Wdec,
           const float* __restrict__ bdec, float* __restrict__ out) {
    __shared__ float tl[32][64];
    const int tid = threadIdx.x;
    const int b0 = blockIdx.y * 32;
    const int m = blockIdx.x * 256 + tid;
    for (int j = tid; j < 32 * 64; j += 256)
        tl[j >> 6][j & 63] = emb[(size_t)b0 * 64 + j];
    __syncthreads();
    if (m >= M_ITEMS) return;
    float acc[32] = {};
    const float* wp = Wdec + (size_t)m * 64;
#pragma unroll
    for (int k = 0; k < 64; k += 4) {
        float4 w = *reinterpret_cast<const float4*>(&wp[k]);
#pragma unroll
        for (int i = 0; i < 32; ++i) {
            acc[i] = fmaf(w.x, tl[i][k + 0], acc[i]);
            acc[i] = fmaf(w.y, tl[i][k + 1], acc[i]);
            acc[i] = fmaf(w.z, tl[i][k + 2], acc[i]);
            acc[i] = fmaf(w.w, tl[i][k + 3], acc[i]);
        }
    }
    float bb = bdec[m];
#pragma unroll
    for (int i = 0; i < 32; ++i)
        out[(size_t)(b0 + i) * M_ITEMS + m] = sigmoidf_(acc[i] + bb);
}

extern "C" void kernel_launch(void* const* d_in, const int* in_sizes, int n_in,
                              void* d_out, int out_size, void* d_ws, size_t ws_size,
                              hipStream_t stream) {
    const int*   x      = (const int*)d_in[0];
    const float* node_x = (const float*)d_in[1];
    const int*   ei     = (const int*)d_in[2];
    const float* rating = (const float*)d_in[3];
    const float* Wenc   = (const float*)d_in[4];
    const float* benc   = (const float*)d_in[5];
    const float* Wdec   = (const float*)d_in[6];
    const float* bdec   = (const float*)d_in[7];
    const float* Wl1    = (const float*)d_in[8];
    const float* bl1    = (const float*)d_in[9];
    const float* Wr1    = (const float*)d_in[10];
    const float* Wl2    = (const float*)d_in[11];
    const float* bl2    = (const float*)d_in[12];
    const float* Wr2    = (const float*)d_in[13];
    const int* src = ei;
    const int* dst = ei + N_EDGES;

    char* p = (char*)d_ws;
    int*   cursor = (int*)p;   p += (size_t)N_NODES * 4;            // zeroed
    int*   slot   = (int*)p;   p += (size_t)N_NODES * CAP * 4;
    float* y1     = (float*)p; p += (size_t)N_NODES * D_HID * 4;
    float* h      = (float*)p; p += (size_t)N_NODES * D_HID * 4;
    float* emb    = (float*)p; p += (size_t)BATCH * D_EMB * 4;
    float* WencT  = (float*)p; p += (size_t)M_ITEMS * D_EMB * 4;
    float* part   = (float*)p; p += (size_t)4 * BATCH * D_EMB * 4;

    hipMemsetAsync(cursor, 0, (size_t)N_NODES * 4, stream);

    k_fill<<<(N_EDGES + 255) / 256, 256, 0, stream>>>(src, dst, cursor, slot);
    k_transpose<<<(D_EMB * M_ITEMS + 255) / 256, 256, 0, stream>>>(Wenc, WencT);

    // y1 = node_x @ Wl1^T   [50000,32]
    k_xw<64, 32><<<(N_NODES * 32 + 255) / 256, 256, 0, stream>>>(
        node_x, Wl1, y1, N_NODES);
    // h = relu(gather(y1)/deg + bl1 + node_x @ Wr1^T)   [50000,32]
    k_node1<<<N_NODES / 8, 256, 0, stream>>>(
        node_x, y1, cursor, slot, Wr1, bl1, h);
    // partial encoder GEMV (rows 32/block, K split 4)
    dim3 genc(BATCH / 32, 4);
    k_enc_part<<<genc, 512, 0, stream>>>(x, rating, WencT, part);
    // emb = sigmoid(partials + benc + gather(h)/deg@Wl2^T + bl2 + h[x]@Wr2^T)
    k_comb<<<BATCH / 8, 512, 0, stream>>>(
        x, part, benc, cursor, slot, h, Wl2, bl2, Wr2, emb);
    // out = sigmoid(emb @ Wdec^T + bdec)   [4096,5000]
    dim3 gdec((M_ITEMS + 255) / 256, BATCH / 32);
    k_dec<<<gdec, 256, 0, stream>>>(emb, Wdec, bdec, (float*)d_out);
}